// Round 5
// baseline (2525.287 us; speedup 1.0000x reference)
//
#include <hip/hip_runtime.h>
#include <hip/hip_bf16.h>

#define N_NODES 100000
#define N_EDGES 3200000
#define D 128
#define NB 1563         // buckets: bin = row >> 6 (64 rows per bucket)
#define CAP 2560        // bucket capacity (mean 2048, sigma ~45 -> +11 sigma)
#define EPB 16          // edges per thread in partition_k (256 thr -> 4096/block)

typedef __attribute__((ext_vector_type(8))) short short8v;   // 8 bf16 (4 VGPRs)
typedef __attribute__((ext_vector_type(4))) float f32x4;

static __device__ __forceinline__ short f2bf(float f) {
    __hip_bfloat16 h = __float2bfloat16(f);
    return __builtin_bit_cast(short, h);
}

// ---------------- init bucket cursors ----------------
__global__ __launch_bounds__(256) void init_cursor(int* __restrict__ cursor) {
    int i = blockIdx.x * 256 + threadIdx.x;
    if (i < NB) cursor[i] = i * CAP;
}

// ---------------- pass 1: partition edges into 64-row buckets ----------------
// Single read of ei; rec/rank/bin kept in registers. One global atomicAdd per
// (block,bucket) run reservation.
__global__ __launch_bounds__(256) void partition_k(const int* __restrict__ ei,
                                                   int* __restrict__ cursor,
                                                   int* __restrict__ staging) {
    __shared__ int lbin[NB];
    int tid = threadIdx.x;
    long long base = (long long)blockIdx.x * (256 * EPB);

    for (int i = tid; i < NB; i += 256) lbin[i] = 0;
    __syncthreads();

    int lrec[EPB];   // (col<<6)|(row&63)
    int lpk[EPB];    // (bin<<16)|rank
#pragma unroll
    for (int j = 0; j < EPB; ++j) {
        long long e = base + j * 256 + tid;
        lpk[j] = -1;
        if (e < N_EDGES) {
            int r = ei[e];
            int c = ei[N_EDGES + e];
            int bin = r >> 6;
            int rank = atomicAdd(&lbin[bin], 1);
            lrec[j] = (c << 6) | (r & 63);
            lpk[j] = (bin << 16) | rank;
        }
    }
    __syncthreads();
    // reserve runs
    for (int i = tid; i < NB; i += 256) {
        int c = lbin[i];
        if (c > 0) lbin[i] = atomicAdd(&cursor[i], c);
    }
    __syncthreads();
#pragma unroll
    for (int j = 0; j < EPB; ++j) {
        if (lpk[j] >= 0) {
            int bin = ((unsigned)lpk[j]) >> 16;
            int rank = lpk[j] & 0xffff;
            staging[lbin[bin] + rank] = lrec[j];
        }
    }
}

// ---------------- per-bucket degree hist -> dinv ----------------
__global__ __launch_bounds__(256) void hist_dinv_k(const int* __restrict__ staging,
                                                   const int* __restrict__ cursor,
                                                   float* __restrict__ dinv) {
    __shared__ int hist[64];
    int bin = blockIdx.x;
    int tid = threadIdx.x;
    int cnt = cursor[bin] - bin * CAP;
    const int* st = staging + bin * CAP;

    if (tid < 64) hist[tid] = 0;
    __syncthreads();
    for (int i = tid; i < cnt; i += 256)
        atomicAdd(&hist[st[i] & 63], 1);
    __syncthreads();
    if (tid < 64) {
        int row = (bin << 6) + tid;
        if (row < N_NODES) {
            int deg = hist[tid];
            dinv[row] = (deg > 0) ? rsqrtf((float)deg) : 0.0f;
        }
    }
}

// ---------------- W f32 -> bf16 ----------------
__global__ __launch_bounds__(256) void convW(const float* __restrict__ W,
                                             __hip_bfloat16* __restrict__ Wb) {
    int i = blockIdx.x * 256 + threadIdx.x;
    if (i < D * D) Wb[i] = __float2bfloat16(W[i]);
}

// ---------------- xl = bf16(x @ W.T + b), MFMA 16x16x32 ----------------
__global__ __launch_bounds__(256) void gemm_mfma(const float* __restrict__ x,
                                                 const __hip_bfloat16* __restrict__ Wb,
                                                 const float* __restrict__ b,
                                                 __hip_bfloat16* __restrict__ xl) {
    __shared__ __hip_bfloat16 lds[4][16][136];   // per-wave transpose buffer
    int tid = threadIdx.x;
    int w = tid >> 6;
    int l = tid & 63;
    int lm = l & 15;
    int kb = l >> 4;
    int bm = blockIdx.x * 64 + w * 16;

    int row = bm + lm;
    if (row >= N_NODES) row = N_NODES - 1;       // dup compute; stores guarded
    const float* xr = x + (size_t)row * D;

    short8v a[4];
#pragma unroll
    for (int ks = 0; ks < 4; ++ks) {
        const float* p = xr + ks * 32 + kb * 8;
        float4 u = *(const float4*)p;
        float4 v = *(const float4*)(p + 4);
        short8v t;
        t[0] = f2bf(u.x); t[1] = f2bf(u.y); t[2] = f2bf(u.z); t[3] = f2bf(u.w);
        t[4] = f2bf(v.x); t[5] = f2bf(v.y); t[6] = f2bf(v.z); t[7] = f2bf(v.w);
        a[ks] = t;
    }

    f32x4 acc[8];
#pragma unroll
    for (int nf = 0; nf < 8; ++nf) {
        acc[nf][0] = 0.f; acc[nf][1] = 0.f; acc[nf][2] = 0.f; acc[nf][3] = 0.f;
    }

    const short8v* Wv = reinterpret_cast<const short8v*>(Wb);
#pragma unroll
    for (int ks = 0; ks < 4; ++ks) {
#pragma unroll
        for (int nf = 0; nf < 8; ++nf) {
            short8v bf = Wv[(nf * 16 + lm) * 16 + ks * 4 + kb];
            acc[nf] = __builtin_amdgcn_mfma_f32_16x16x32_bf16(a[ks], bf, acc[nf], 0, 0, 0);
        }
    }

#pragma unroll
    for (int nf = 0; nf < 8; ++nf) {
        float bias = b[nf * 16 + lm];
#pragma unroll
        for (int j = 0; j < 4; ++j) {
            lds[w][kb * 4 + j][nf * 16 + lm] = __float2bfloat16(acc[nf][j] + bias);
        }
    }
    __syncthreads();
#pragma unroll
    for (int it = 0; it < 4; ++it) {
        int idx = it * 64 + l;
        int r = idx >> 4;
        int ch = (idx & 15) * 8;
        int grow = bm + r;
        if (grow < N_NODES)
            *(short8v*)&xl[(size_t)grow * D + ch] = *(const short8v*)&lds[w][r][ch];
    }
}

// ---------------- bucketed aggregation: LDS accumulator tile ----------------
// One block per 64-row bucket. out[r] = dinv[r] * sum_e dinv[c_e] * xl[c_e].
__global__ __launch_bounds__(256) void aggregate_bucket(const int* __restrict__ staging,
                                                        const int* __restrict__ cursor,
                                                        const float* __restrict__ dinv,
                                                        const unsigned int* __restrict__ xl2,
                                                        float* __restrict__ out) {
    __shared__ float tile[64][128];              // 32 KB accumulator
    int bin = blockIdx.x;
    int tid = threadIdx.x;
    int w = tid >> 6;
    int lane = tid & 63;

    // zero tile
    float4* t4 = (float4*)&tile[0][0];
    for (int i = tid; i < 64 * 128 / 4; i += 256) t4[i] = make_float4(0.f, 0.f, 0.f, 0.f);
    __syncthreads();

    int cnt = cursor[bin] - bin * CAP;
    const int* st = staging + bin * CAP;
    const unsigned int* xb = xl2 + lane;

    int chunk = (cnt + 3) >> 2;
    int lo = __builtin_amdgcn_readfirstlane(w * chunk);
    int hi = __builtin_amdgcn_readfirstlane(min(cnt, lo + chunk));

    int i = lo;
    for (; i + 8 <= hi; i += 8) {
        int recs[8];
        float wcs[8];
        unsigned int vs[8];
#pragma unroll
        for (int k = 0; k < 8; ++k) recs[k] = st[i + k];
#pragma unroll
        for (int k = 0; k < 8; ++k) {
            int c = ((unsigned)recs[k]) >> 6;
            wcs[k] = dinv[c];
            vs[k] = xb[(size_t)c * 64];
        }
#pragma unroll
        for (int k = 0; k < 8; ++k) {
            int r = recs[k] & 63;
            float fx = __uint_as_float(vs[k] << 16);
            float fy = __uint_as_float(vs[k] & 0xffff0000u);
            atomicAdd(&tile[r][2 * lane], wcs[k] * fx);
            atomicAdd(&tile[r][2 * lane + 1], wcs[k] * fy);
        }
    }
    for (; i < hi; ++i) {
        int rec = st[i];
        int c = ((unsigned)rec) >> 6;
        int r = rec & 63;
        float wc = dinv[c];
        unsigned int v = xb[(size_t)c * 64];
        atomicAdd(&tile[r][2 * lane], wc * __uint_as_float(v << 16));
        atomicAdd(&tile[r][2 * lane + 1], wc * __uint_as_float(v & 0xffff0000u));
    }
    __syncthreads();

    // scale by dinv[row], write coalesced
    int row0 = bin << 6;
    for (int idx = tid; idx < 64 * 32; idx += 256) {
        int r = idx >> 5;
        int m = idx & 31;
        int row = row0 + r;
        if (row < N_NODES) {
            float dr = dinv[row];
            float4 t = ((const float4*)&tile[r][0])[m];
            t.x *= dr; t.y *= dr; t.z *= dr; t.w *= dr;
            ((float4*)&out[(size_t)row * D])[m] = t;
        }
    }
}

extern "C" void kernel_launch(void* const* d_in, const int* in_sizes, int n_in,
                              void* d_out, int out_size, void* d_ws, size_t ws_size,
                              hipStream_t stream) {
    const float* x  = (const float*)d_in[0];
    const int*   ei = (const int*)d_in[1];
    const float* W  = (const float*)d_in[2];
    const float* b  = (const float*)d_in[3];
    float* out = (float*)d_out;

    // workspace layout (4-byte units)
    unsigned int* ws = (unsigned int*)d_ws;
    __hip_bfloat16* xl = (__hip_bfloat16*)ws;                 // 12.8M bf16 = 6.4M u32
    __hip_bfloat16* Wb = (__hip_bfloat16*)(ws + 6400000);     // 16384 bf16 = 8192 u32
    float* dinv    = (float*)(ws + 6408192);                  // 100,096
    int*   cursor  = (int*)(ws + 6508288);                    // 1,600 (NB=1563)
    int*   staging = (int*)(ws + 6509888);                    // NB*CAP = 4,001,280 ints
    // total ≈ 10.5M u32 ≈ 42 MB

    init_cursor<<<(NB + 255) / 256, 256, 0, stream>>>(cursor);

    const int pblocks = (N_EDGES + 256 * EPB - 1) / (256 * EPB);   // 782
    partition_k<<<pblocks, 256, 0, stream>>>(ei, cursor, staging);

    hist_dinv_k<<<NB, 256, 0, stream>>>(staging, cursor, dinv);

    convW<<<(D * D + 255) / 256, 256, 0, stream>>>(W, Wb);

    gemm_mfma<<<(N_NODES + 63) / 64, 256, 0, stream>>>(x, Wb, b, xl);

    aggregate_bucket<<<NB, 256, 0, stream>>>(
        staging, cursor, dinv, (const unsigned int*)xl, out);
}

// Round 6
// 319.677 us; speedup vs baseline: 7.8995x; 7.8995x over previous
//
#include <hip/hip_runtime.h>
#include <hip/hip_bf16.h>

#define N_NODES 100000
#define N_EDGES 3200000
#define D 128
#define NB 782          // buckets: bin = row >> 7 (128 rows per bucket)
#define CAP 5120        // bucket capacity = 20*256 (mean 4092, sigma ~64)
#define EPB 16          // edges per thread in partition_k (256 thr -> 4096/block)
#define K2 20           // records stashed per thread in pass2 (20*256 = CAP)

typedef __attribute__((ext_vector_type(8))) short short8v;   // 8 bf16 (4 VGPRs)
typedef __attribute__((ext_vector_type(4))) float f32x4;

static __device__ __forceinline__ short f2bf(float f) {
    __hip_bfloat16 h = __float2bfloat16(f);
    return __builtin_bit_cast(short, h);
}

// ---------------- init bucket cursors ----------------
__global__ __launch_bounds__(256) void init_cursor(int* __restrict__ cursor) {
    int i = blockIdx.x * 256 + threadIdx.x;
    if (i < NB) cursor[i] = i * CAP;
}

// ---------------- pass 1: partition edges into 128-row buckets ----------------
// Single read of ei; rec/rank/bin kept in registers. One global atomicAdd per
// (block,bucket) run reservation.
__global__ __launch_bounds__(256) void partition_k(const int* __restrict__ ei,
                                                   int* __restrict__ cursor,
                                                   int* __restrict__ staging) {
    __shared__ int lbin[NB];
    int tid = threadIdx.x;
    long long base = (long long)blockIdx.x * (256 * EPB);

    for (int i = tid; i < NB; i += 256) lbin[i] = 0;
    __syncthreads();

    int lrec[EPB];   // (col<<7)|(row&127)
    int lpk[EPB];    // (bin<<16)|rank
#pragma unroll
    for (int j = 0; j < EPB; ++j) {
        long long e = base + j * 256 + tid;
        lpk[j] = -1;
        if (e < N_EDGES) {
            int r = ei[e];
            int c = ei[N_EDGES + e];
            int bin = r >> 7;
            int rank = atomicAdd(&lbin[bin], 1);
            lrec[j] = (c << 7) | (r & 127);
            lpk[j] = (bin << 16) | rank;
        }
    }
    __syncthreads();
    // reserve runs
    for (int i = tid; i < NB; i += 256) {
        int c = lbin[i];
        if (c > 0) lbin[i] = atomicAdd(&cursor[i], c);
    }
    __syncthreads();
#pragma unroll
    for (int j = 0; j < EPB; ++j) {
        if (lpk[j] >= 0) {
            int bin = ((unsigned)lpk[j]) >> 16;
            int rank = lpk[j] & 0xffff;
            staging[lbin[bin] + rank] = lrec[j];
        }
    }
}

// ---------------- scan bucket counts -> final CSR bases ----------------
__global__ __launch_bounds__(1024) void bscan_k(const int* __restrict__ cursor,
                                                int* __restrict__ fbase) {
    __shared__ int s[1024];
    int tid = threadIdx.x;
    int v = (tid < NB) ? (cursor[tid] - tid * CAP) : 0;
    s[tid] = v;
    __syncthreads();
    for (int off = 1; off < 1024; off <<= 1) {
        int t = (tid >= off) ? s[tid - off] : 0;
        __syncthreads();
        s[tid] += t;
        __syncthreads();
    }
    if (tid < NB) fbase[tid] = s[tid] - v;       // exclusive
}

// ---------------- pass 2: per-bucket CSR sort + rowptr + dinv ----------------
// Records stashed in registers: staging read ONCE.
__global__ __launch_bounds__(256) void pass2_k(const int* __restrict__ staging,
                                               const int* __restrict__ cursor,
                                               const int* __restrict__ fbase,
                                               int* __restrict__ rowptr,
                                               float* __restrict__ dinv,
                                               int* __restrict__ edgesF) {
    __shared__ int hist[128];
    __shared__ int ssc[128];
    int bin = blockIdx.x;
    int tid = threadIdx.x;
    int cnt = cursor[bin] - bin * CAP;
    int fb = fbase[bin];
    int row0 = bin << 7;
    const int* st = staging + bin * CAP;

    if (tid < 128) hist[tid] = 0;
    __syncthreads();

    int myrec[K2];
    int myrank[K2];
#pragma unroll
    for (int k = 0; k < K2; ++k) {
        int idx = k * 256 + tid;
        myrec[k] = (idx < cnt) ? st[idx] : -1;
    }
#pragma unroll
    for (int k = 0; k < K2; ++k) {
        myrank[k] = (myrec[k] >= 0) ? atomicAdd(&hist[myrec[k] & 127], 1) : 0;
    }
    __syncthreads();
    if (tid < 128) ssc[tid] = hist[tid];
    __syncthreads();
    for (int off = 1; off < 128; off <<= 1) {
        int t = (tid < 128 && tid >= off) ? ssc[tid - off] : 0;
        __syncthreads();
        if (tid < 128) ssc[tid] += t;
        __syncthreads();
    }
    // ssc inclusive; exclusive base = ssc[r] - hist[r]
    if (tid < 128) {
        int row = row0 + tid;
        if (row < N_NODES) {
            int deg = hist[tid];
            rowptr[row] = fb + ssc[tid] - deg;
            dinv[row] = (deg > 0) ? rsqrtf((float)deg) : 0.0f;
        }
    }
    if (bin == 0 && tid == 0) rowptr[N_NODES] = N_EDGES;
    __syncthreads();
#pragma unroll
    for (int k = 0; k < K2; ++k) {
        if (myrec[k] >= 0) {
            int r = myrec[k] & 127;
            int c = ((unsigned)myrec[k]) >> 7;
            edgesF[fb + ssc[r] - hist[r] + myrank[k]] = c;
        }
    }
}

// ---------------- W f32 -> bf16 ----------------
__global__ __launch_bounds__(256) void convW(const float* __restrict__ W,
                                             __hip_bfloat16* __restrict__ Wb) {
    int i = blockIdx.x * 256 + threadIdx.x;
    if (i < D * D) Wb[i] = __float2bfloat16(W[i]);
}

// ---------------- xls = bf16(dinv[row] * (x @ W.T + b)), MFMA 16x16x32 ----------------
__global__ __launch_bounds__(256) void gemm_mfma(const float* __restrict__ x,
                                                 const __hip_bfloat16* __restrict__ Wb,
                                                 const float* __restrict__ b,
                                                 const float* __restrict__ dinv,
                                                 __hip_bfloat16* __restrict__ xl) {
    __shared__ __hip_bfloat16 lds[4][16][136];   // per-wave transpose buffer
    int tid = threadIdx.x;
    int w = tid >> 6;
    int l = tid & 63;
    int lm = l & 15;
    int kb = l >> 4;
    int bm = blockIdx.x * 64 + w * 16;

    int row = bm + lm;
    if (row >= N_NODES) row = N_NODES - 1;       // dup compute; stores guarded
    const float* xr = x + (size_t)row * D;

    short8v a[4];
#pragma unroll
    for (int ks = 0; ks < 4; ++ks) {
        const float* p = xr + ks * 32 + kb * 8;
        float4 u = *(const float4*)p;
        float4 v = *(const float4*)(p + 4);
        short8v t;
        t[0] = f2bf(u.x); t[1] = f2bf(u.y); t[2] = f2bf(u.z); t[3] = f2bf(u.w);
        t[4] = f2bf(v.x); t[5] = f2bf(v.y); t[6] = f2bf(v.z); t[7] = f2bf(v.w);
        a[ks] = t;
    }

    f32x4 acc[8];
#pragma unroll
    for (int nf = 0; nf < 8; ++nf) {
        acc[nf][0] = 0.f; acc[nf][1] = 0.f; acc[nf][2] = 0.f; acc[nf][3] = 0.f;
    }

    const short8v* Wv = reinterpret_cast<const short8v*>(Wb);
#pragma unroll
    for (int ks = 0; ks < 4; ++ks) {
#pragma unroll
        for (int nf = 0; nf < 8; ++nf) {
            short8v bf = Wv[(nf * 16 + lm) * 16 + ks * 4 + kb];
            acc[nf] = __builtin_amdgcn_mfma_f32_16x16x32_bf16(a[ks], bf, acc[nf], 0, 0, 0);
        }
    }

    // per-output-row dinv scale (D row = kb*4 + j)
    float drj[4];
#pragma unroll
    for (int j = 0; j < 4; ++j) {
        int rr = bm + kb * 4 + j;
        if (rr >= N_NODES) rr = N_NODES - 1;
        drj[j] = dinv[rr];
    }

#pragma unroll
    for (int nf = 0; nf < 8; ++nf) {
        float bias = b[nf * 16 + lm];
#pragma unroll
        for (int j = 0; j < 4; ++j) {
            lds[w][kb * 4 + j][nf * 16 + lm] =
                __float2bfloat16((acc[nf][j] + bias) * drj[j]);
        }
    }
    __syncthreads();
#pragma unroll
    for (int it = 0; it < 4; ++it) {
        int idx = it * 64 + l;
        int r = idx >> 4;
        int ch = (idx & 15) * 8;
        int grow = bm + r;
        if (grow < N_NODES)
            *(short8v*)&xl[(size_t)grow * D + ch] = *(const short8v*)&lds[w][r][ch];
    }
}

// ---------------- aggregation: one wave per node, bf16x2 per lane ----------------
// out[r] = dinv[r] * sum_e xls[c_e]   (dinv[c] pre-folded into xls)
__global__ __launch_bounds__(256) void aggregate(const int* __restrict__ edges,
                                                 const int* __restrict__ rowptr,
                                                 const float* __restrict__ dinv,
                                                 const unsigned int* __restrict__ xl2,
                                                 float* __restrict__ out) {
    int gw = (blockIdx.x * 256 + threadIdx.x) >> 6;
    int lane = threadIdx.x & 63;
    if (gw >= N_NODES) return;
    int s = rowptr[gw];
    int e = rowptr[gw + 1];
    float ax = 0.0f, ay = 0.0f;
    int i = s;
    for (; i + 4 <= e; i += 4) {
        int c0 = edges[i], c1 = edges[i + 1], c2 = edges[i + 2], c3 = edges[i + 3];
        unsigned int v0 = xl2[c0 * 64 + lane];
        unsigned int v1 = xl2[c1 * 64 + lane];
        unsigned int v2 = xl2[c2 * 64 + lane];
        unsigned int v3 = xl2[c3 * 64 + lane];
        ax += __uint_as_float(v0 << 16);
        ay += __uint_as_float(v0 & 0xffff0000u);
        ax += __uint_as_float(v1 << 16);
        ay += __uint_as_float(v1 & 0xffff0000u);
        ax += __uint_as_float(v2 << 16);
        ay += __uint_as_float(v2 & 0xffff0000u);
        ax += __uint_as_float(v3 << 16);
        ay += __uint_as_float(v3 & 0xffff0000u);
    }
    for (; i < e; ++i) {
        unsigned int v0 = xl2[edges[i] * 64 + lane];
        ax += __uint_as_float(v0 << 16);
        ay += __uint_as_float(v0 & 0xffff0000u);
    }
    float dr = dinv[gw];
    float2 r;
    r.x = dr * ax;
    r.y = dr * ay;
    *(float2*)&out[(size_t)gw * D + lane * 2] = r;
}

extern "C" void kernel_launch(void* const* d_in, const int* in_sizes, int n_in,
                              void* d_out, int out_size, void* d_ws, size_t ws_size,
                              hipStream_t stream) {
    const float* x  = (const float*)d_in[0];
    const int*   ei = (const int*)d_in[1];
    const float* W  = (const float*)d_in[2];
    const float* b  = (const float*)d_in[3];
    float* out = (float*)d_out;

    // workspace layout (4-byte units)
    unsigned int* ws = (unsigned int*)d_ws;
    __hip_bfloat16* xl = (__hip_bfloat16*)ws;                 // 12.8M bf16 = 6.4M u32
    __hip_bfloat16* Wb = (__hip_bfloat16*)(ws + 6400000);     // 16384 bf16 = 8192 u32
    float* dinv    = (float*)(ws + 6408192);                  // 100,096
    int*   rowptr  = (int*)(ws + 6508288);                    // 100,160 (needs 100,001)
    int*   cursor  = (int*)(ws + 6608448);                    // 800 (NB=782)
    int*   fbase   = (int*)(ws + 6609248);                    // 800
    int*   edgesF  = (int*)(ws + 6610048);                    // 3.2M ints
    int*   staging = (int*)(ws + 9810048);                    // NB*CAP = 4,003,840 ints
    // total ≈ 13.8M u32 ≈ 55.3 MB

    init_cursor<<<(NB + 255) / 256, 256, 0, stream>>>(cursor);

    const int pblocks = (N_EDGES + 256 * EPB - 1) / (256 * EPB);   // 782
    partition_k<<<pblocks, 256, 0, stream>>>(ei, cursor, staging);

    bscan_k<<<1, 1024, 0, stream>>>(cursor, fbase);

    pass2_k<<<NB, 256, 0, stream>>>(staging, cursor, fbase, rowptr, dinv, edgesF);

    convW<<<(D * D + 255) / 256, 256, 0, stream>>>(W, Wb);

    gemm_mfma<<<(N_NODES + 63) / 64, 256, 0, stream>>>(x, Wb, b, dinv, xl);

    aggregate<<<(N_NODES * 64 + 255) / 256, 256, 0, stream>>>(
        edgesF, rowptr, dinv, (const unsigned int*)xl, out);
}

// Round 7
// 318.758 us; speedup vs baseline: 7.9223x; 1.0029x over previous
//
#include <hip/hip_runtime.h>
#include <hip/hip_bf16.h>

#define N_NODES 100000
#define N_EDGES 3200000
#define D 128
#define NB 782          // buckets: bin = row >> 7 (128 rows per bucket)
#define CAP 5120        // bucket capacity = 20*256 (mean 4092, sigma ~64)
#define EPB 32          // edges per thread in partition_k (256 thr -> 8192/block)
#define K2 20           // records stashed per thread in pass2 (20*256 = CAP)

typedef __attribute__((ext_vector_type(8))) short short8v;   // 8 bf16 (4 VGPRs)
typedef __attribute__((ext_vector_type(4))) float f32x4;

static __device__ __forceinline__ short f2bf(float f) {
    __hip_bfloat16 h = __float2bfloat16(f);
    return __builtin_bit_cast(short, h);
}

// ---------------- pass 1: partition edges into 128-row buckets ----------------
// cursor[] holds per-bucket COUNTS (memset to 0); staging base = bin*CAP + old.
__global__ __launch_bounds__(256) void partition_k(const int* __restrict__ ei,
                                                   int* __restrict__ cursor,
                                                   int* __restrict__ staging) {
    __shared__ int lbin[NB];
    int tid = threadIdx.x;
    long long base = (long long)blockIdx.x * (256 * EPB);

    for (int i = tid; i < NB; i += 256) lbin[i] = 0;
    __syncthreads();

    int lrec[EPB];   // (col<<7)|(row&127)
    int lpk[EPB];    // (bin<<16)|rank
#pragma unroll
    for (int j = 0; j < EPB; ++j) {
        long long e = base + j * 256 + tid;
        lpk[j] = -1;
        if (e < N_EDGES) {
            int r = ei[e];
            int c = ei[N_EDGES + e];
            int bin = r >> 7;
            int rank = atomicAdd(&lbin[bin], 1);
            lrec[j] = (c << 7) | (r & 127);
            lpk[j] = (bin << 16) | rank;
        }
    }
    __syncthreads();
    // reserve runs: lbin becomes global base for this block's run
    for (int i = tid; i < NB; i += 256) {
        int c = lbin[i];
        if (c > 0) lbin[i] = i * CAP + atomicAdd(&cursor[i], c);
    }
    __syncthreads();
#pragma unroll
    for (int j = 0; j < EPB; ++j) {
        if (lpk[j] >= 0) {
            int bin = ((unsigned)lpk[j]) >> 16;
            int rank = lpk[j] & 0xffff;
            staging[lbin[bin] + rank] = lrec[j];
        }
    }
}

// ---------------- single-wave scan of bucket counts -> CSR bases ----------------
__global__ __launch_bounds__(64) void bscan_k(const int* __restrict__ cursor,
                                              int* __restrict__ fbase) {
    int lane = threadIdx.x;          // 0..63
    const int CH = (NB + 63) / 64;   // 13
    int v[CH];
    int t = 0;
#pragma unroll
    for (int k = 0; k < CH; ++k) {
        int idx = lane * CH + k;
        int c = (idx < NB) ? cursor[idx] : 0;
        v[k] = t;                    // prefix within lane chunk (exclusive)
        t += c;
    }
    int x = t;
    for (int off = 1; off < 64; off <<= 1) {
        int y = __shfl_up(x, off, 64);
        if (lane >= off) x += y;
    }
    int excl = x - t;                // exclusive scan of lane totals
#pragma unroll
    for (int k = 0; k < CH; ++k) {
        int idx = lane * CH + k;
        if (idx < NB) fbase[idx] = excl + v[k];
    }
}

// ---------------- pass 2: per-bucket CSR sort + rowptr + dinv ----------------
__global__ __launch_bounds__(256) void pass2_k(const int* __restrict__ staging,
                                               const int* __restrict__ cursor,
                                               const int* __restrict__ fbase,
                                               int* __restrict__ rowptr,
                                               float* __restrict__ dinv,
                                               int* __restrict__ edgesF) {
    __shared__ int hist[128];
    __shared__ int ssc[128];
    int bin = blockIdx.x;
    int tid = threadIdx.x;
    int cnt = cursor[bin];
    int fb = fbase[bin];
    int row0 = bin << 7;
    const int* st = staging + bin * CAP;

    if (tid < 128) hist[tid] = 0;
    __syncthreads();

    int myrec[K2];
    int myrank[K2];
#pragma unroll
    for (int k = 0; k < K2; ++k) {
        int idx = k * 256 + tid;
        myrec[k] = (idx < cnt) ? st[idx] : -1;
    }
#pragma unroll
    for (int k = 0; k < K2; ++k) {
        myrank[k] = (myrec[k] >= 0) ? atomicAdd(&hist[myrec[k] & 127], 1) : 0;
    }
    __syncthreads();
    if (tid < 128) ssc[tid] = hist[tid];
    __syncthreads();
    for (int off = 1; off < 128; off <<= 1) {
        int t = (tid < 128 && tid >= off) ? ssc[tid - off] : 0;
        __syncthreads();
        if (tid < 128) ssc[tid] += t;
        __syncthreads();
    }
    // ssc inclusive; exclusive base = ssc[r] - hist[r]
    if (tid < 128) {
        int row = row0 + tid;
        if (row < N_NODES) {
            int deg = hist[tid];
            rowptr[row] = fb + ssc[tid] - deg;
            dinv[row] = (deg > 0) ? rsqrtf((float)deg) : 0.0f;
        }
    }
    if (bin == 0 && tid == 0) rowptr[N_NODES] = N_EDGES;
    __syncthreads();
#pragma unroll
    for (int k = 0; k < K2; ++k) {
        if (myrec[k] >= 0) {
            int r = myrec[k] & 127;
            int c = ((unsigned)myrec[k]) >> 7;
            edgesF[fb + ssc[r] - hist[r] + myrank[k]] = c;
        }
    }
}

// ---------------- W f32 -> bf16 ----------------
__global__ __launch_bounds__(256) void convW(const float* __restrict__ W,
                                             __hip_bfloat16* __restrict__ Wb) {
    int i = blockIdx.x * 256 + threadIdx.x;
    if (i < D * D) Wb[i] = __float2bfloat16(W[i]);
}

// ---------------- xls = bf16(dinv[row] * (x @ W.T + b)), MFMA 16x16x32 ----------------
__global__ __launch_bounds__(256) void gemm_mfma(const float* __restrict__ x,
                                                 const __hip_bfloat16* __restrict__ Wb,
                                                 const float* __restrict__ b,
                                                 const float* __restrict__ dinv,
                                                 __hip_bfloat16* __restrict__ xl) {
    __shared__ __hip_bfloat16 lds[4][16][136];   // per-wave transpose buffer
    int tid = threadIdx.x;
    int w = tid >> 6;
    int l = tid & 63;
    int lm = l & 15;
    int kb = l >> 4;
    int bm = blockIdx.x * 64 + w * 16;

    int row = bm + lm;
    if (row >= N_NODES) row = N_NODES - 1;       // dup compute; stores guarded
    const float* xr = x + (size_t)row * D;

    short8v a[4];
#pragma unroll
    for (int ks = 0; ks < 4; ++ks) {
        const float* p = xr + ks * 32 + kb * 8;
        float4 u = *(const float4*)p;
        float4 v = *(const float4*)(p + 4);
        short8v t;
        t[0] = f2bf(u.x); t[1] = f2bf(u.y); t[2] = f2bf(u.z); t[3] = f2bf(u.w);
        t[4] = f2bf(v.x); t[5] = f2bf(v.y); t[6] = f2bf(v.z); t[7] = f2bf(v.w);
        a[ks] = t;
    }

    f32x4 acc[8];
#pragma unroll
    for (int nf = 0; nf < 8; ++nf) {
        acc[nf][0] = 0.f; acc[nf][1] = 0.f; acc[nf][2] = 0.f; acc[nf][3] = 0.f;
    }

    const short8v* Wv = reinterpret_cast<const short8v*>(Wb);
#pragma unroll
    for (int ks = 0; ks < 4; ++ks) {
#pragma unroll
        for (int nf = 0; nf < 8; ++nf) {
            short8v bf = Wv[(nf * 16 + lm) * 16 + ks * 4 + kb];
            acc[nf] = __builtin_amdgcn_mfma_f32_16x16x32_bf16(a[ks], bf, acc[nf], 0, 0, 0);
        }
    }

    // per-output-row dinv scale (D row = kb*4 + j)
    float drj[4];
#pragma unroll
    for (int j = 0; j < 4; ++j) {
        int rr = bm + kb * 4 + j;
        if (rr >= N_NODES) rr = N_NODES - 1;
        drj[j] = dinv[rr];
    }

#pragma unroll
    for (int nf = 0; nf < 8; ++nf) {
        float bias = b[nf * 16 + lm];
#pragma unroll
        for (int j = 0; j < 4; ++j) {
            lds[w][kb * 4 + j][nf * 16 + lm] =
                __float2bfloat16((acc[nf][j] + bias) * drj[j]);
        }
    }
    __syncthreads();
#pragma unroll
    for (int it = 0; it < 4; ++it) {
        int idx = it * 64 + l;
        int r = idx >> 4;
        int ch = (idx & 15) * 8;
        int grow = bm + r;
        if (grow < N_NODES)
            *(short8v*)&xl[(size_t)grow * D + ch] = *(const short8v*)&lds[w][r][ch];
    }
}

// ---------------- aggregation: wave per node, 4 edges/step, 16 lanes x 16B ----------------
// out[r] = dinv[r] * sum_e xls[c_e]   (dinv[c] pre-folded into xls)
__global__ __launch_bounds__(256) void aggregate(const int* __restrict__ edges,
                                                 const int* __restrict__ rowptr,
                                                 const float* __restrict__ dinv,
                                                 const __hip_bfloat16* __restrict__ xl,
                                                 float* __restrict__ out) {
    int gw = (blockIdx.x * 256 + threadIdx.x) >> 6;
    int lane = threadIdx.x & 63;
    if (gw >= N_NODES) return;
    int g = lane >> 4;          // edge-slot group 0..3
    int q = lane & 15;          // 16B chunk within row (8 channels)
    int s = rowptr[gw];
    int e = rowptr[gw + 1];

    float acc[8];
#pragma unroll
    for (int k = 0; k < 8; ++k) acc[k] = 0.0f;

    int i = s;
    for (; i + 4 <= e; i += 4) {
        int c = edges[i + g];                        // 16-way broadcast load
        uint4 v = *(const uint4*)&xl[(size_t)c * D + q * 8];
        acc[0] += __uint_as_float(v.x << 16);
        acc[1] += __uint_as_float(v.x & 0xffff0000u);
        acc[2] += __uint_as_float(v.y << 16);
        acc[3] += __uint_as_float(v.y & 0xffff0000u);
        acc[4] += __uint_as_float(v.z << 16);
        acc[5] += __uint_as_float(v.z & 0xffff0000u);
        acc[6] += __uint_as_float(v.w << 16);
        acc[7] += __uint_as_float(v.w & 0xffff0000u);
    }
    int rem = e - i;
    if (g < rem) {
        int c = edges[i + g];
        uint4 v = *(const uint4*)&xl[(size_t)c * D + q * 8];
        acc[0] += __uint_as_float(v.x << 16);
        acc[1] += __uint_as_float(v.x & 0xffff0000u);
        acc[2] += __uint_as_float(v.y << 16);
        acc[3] += __uint_as_float(v.y & 0xffff0000u);
        acc[4] += __uint_as_float(v.z << 16);
        acc[5] += __uint_as_float(v.z & 0xffff0000u);
        acc[6] += __uint_as_float(v.w << 16);
        acc[7] += __uint_as_float(v.w & 0xffff0000u);
    }
    // reduce across the 4 groups (lanes l, l^16, l^32, l^48)
#pragma unroll
    for (int k = 0; k < 8; ++k) {
        acc[k] += __shfl_xor(acc[k], 16, 64);
        acc[k] += __shfl_xor(acc[k], 32, 64);
    }
    if (lane < 16) {
        float dr = dinv[gw];
        float4 o0 = make_float4(dr * acc[0], dr * acc[1], dr * acc[2], dr * acc[3]);
        float4 o1 = make_float4(dr * acc[4], dr * acc[5], dr * acc[6], dr * acc[7]);
        float* op = &out[(size_t)gw * D + q * 8];
        *(float4*)op = o0;
        *(float4*)(op + 4) = o1;
    }
}

extern "C" void kernel_launch(void* const* d_in, const int* in_sizes, int n_in,
                              void* d_out, int out_size, void* d_ws, size_t ws_size,
                              hipStream_t stream) {
    const float* x  = (const float*)d_in[0];
    const int*   ei = (const int*)d_in[1];
    const float* W  = (const float*)d_in[2];
    const float* b  = (const float*)d_in[3];
    float* out = (float*)d_out;

    // workspace layout (4-byte units)
    unsigned int* ws = (unsigned int*)d_ws;
    __hip_bfloat16* xl = (__hip_bfloat16*)ws;                 // 12.8M bf16 = 6.4M u32
    __hip_bfloat16* Wb = (__hip_bfloat16*)(ws + 6400000);     // 16384 bf16 = 8192 u32
    float* dinv    = (float*)(ws + 6408192);                  // 100,096
    int*   rowptr  = (int*)(ws + 6508288);                    // 100,160 (needs 100,001)
    int*   cursor  = (int*)(ws + 6608448);                    // 800 (NB=782)
    int*   fbase   = (int*)(ws + 6609248);                    // 800
    int*   edgesF  = (int*)(ws + 6610048);                    // 3.2M ints
    int*   staging = (int*)(ws + 9810048);                    // NB*CAP = 4,003,840 ints
    // total ≈ 13.8M u32 ≈ 55.3 MB

    hipMemsetAsync(cursor, 0, NB * sizeof(int), stream);

    const int pblocks = (N_EDGES + 256 * EPB - 1) / (256 * EPB);   // 391
    partition_k<<<pblocks, 256, 0, stream>>>(ei, cursor, staging);

    bscan_k<<<1, 64, 0, stream>>>(cursor, fbase);

    pass2_k<<<NB, 256, 0, stream>>>(staging, cursor, fbase, rowptr, dinv, edgesF);

    convW<<<(D * D + 255) / 256, 256, 0, stream>>>(W, Wb);

    gemm_mfma<<<(N_NODES + 63) / 64, 256, 0, stream>>>(x, Wb, b, dinv, xl);

    aggregate<<<(N_NODES * 64 + 255) / 256, 256, 0, stream>>>(
        edgesF, rowptr, dinv, xl, out);
}

// Round 8
// 300.549 us; speedup vs baseline: 8.4022x; 1.0606x over previous
//
#include <hip/hip_runtime.h>
#include <hip/hip_bf16.h>

#define N_NODES 100000
#define N_EDGES 3200000
#define D 128
#define NB 782          // buckets: bin = row >> 7 (128 rows per bucket)
#define CAP 5120        // bucket capacity = 20*256 (mean 4092, sigma ~64)
#define EPB 32          // edges per thread in partition_k (256 thr -> 8192/block)
#define K2 20           // records stashed per thread in pass2 (20*256 = CAP)

typedef __attribute__((ext_vector_type(8))) short short8v;   // 8 bf16 (4 VGPRs)
typedef __attribute__((ext_vector_type(4))) float f32x4;

static __device__ __forceinline__ short f2bf(float f) {
    __hip_bfloat16 h = __float2bfloat16(f);
    return __builtin_bit_cast(short, h);
}

// ---------------- W f32 -> bf16, + zero bucket counters ----------------
__global__ __launch_bounds__(256) void convW_init(const float* __restrict__ W,
                                                  __hip_bfloat16* __restrict__ Wb,
                                                  int* __restrict__ cursor) {
    int i = blockIdx.x * 256 + threadIdx.x;
    if (i < D * D) Wb[i] = __float2bfloat16(W[i]);
    if (i < NB) cursor[i] = 0;
}

// ---------------- pass 1: partition edges into 128-row buckets ----------------
// cursor[] holds per-bucket COUNTS; staging base = bin*CAP + reserved offset.
__global__ __launch_bounds__(256) void partition_k(const int* __restrict__ ei,
                                                   int* __restrict__ cursor,
                                                   int* __restrict__ staging) {
    __shared__ int lbin[NB];
    int tid = threadIdx.x;
    long long base = (long long)blockIdx.x * (256 * EPB);

    for (int i = tid; i < NB; i += 256) lbin[i] = 0;
    __syncthreads();

    int lrec[EPB];   // (col<<7)|(row&127)
    int lpk[EPB];    // (bin<<16)|rank
#pragma unroll
    for (int j = 0; j < EPB; ++j) {
        long long e = base + j * 256 + tid;
        lpk[j] = -1;
        if (e < N_EDGES) {
            int r = ei[e];
            int c = ei[N_EDGES + e];
            int bin = r >> 7;
            int rank = atomicAdd(&lbin[bin], 1);
            lrec[j] = (c << 7) | (r & 127);
            lpk[j] = (bin << 16) | rank;
        }
    }
    __syncthreads();
    // reserve runs: lbin becomes global base for this block's run
    for (int i = tid; i < NB; i += 256) {
        int c = lbin[i];
        if (c > 0) lbin[i] = i * CAP + atomicAdd(&cursor[i], c);
    }
    __syncthreads();
#pragma unroll
    for (int j = 0; j < EPB; ++j) {
        if (lpk[j] >= 0) {
            int bin = ((unsigned)lpk[j]) >> 16;
            int rank = lpk[j] & 0xffff;
            staging[lbin[bin] + rank] = lrec[j];
        }
    }
}

// ---------------- pass 2: per-bucket CSR sort + rowptr + dinv ----------------
// fbase computed in-block: fb = sum(cursor[0..bin)) — cursor is L2-hot.
__global__ __launch_bounds__(256) void pass2_k(const int* __restrict__ staging,
                                               const int* __restrict__ cursor,
                                               int* __restrict__ rowptr,
                                               float* __restrict__ dinv,
                                               int* __restrict__ edgesF) {
    __shared__ int hist[128];
    __shared__ int ssc[128];
    __shared__ int wsum[4];
    int bin = blockIdx.x;
    int tid = threadIdx.x;
    int cnt = cursor[bin];
    int row0 = bin << 7;
    const int* st = staging + bin * CAP;

    // fb = exclusive prefix of counts
    int pacc = 0;
    for (int j = tid; j < bin; j += 256) pacc += cursor[j];
#pragma unroll
    for (int off = 32; off > 0; off >>= 1) pacc += __shfl_down(pacc, off, 64);
    if ((tid & 63) == 0) wsum[tid >> 6] = pacc;
    if (tid < 128) hist[tid] = 0;
    __syncthreads();
    int fb = wsum[0] + wsum[1] + wsum[2] + wsum[3];

    int myrec[K2];
    int myrank[K2];
#pragma unroll
    for (int k = 0; k < K2; ++k) {
        int idx = k * 256 + tid;
        myrec[k] = (idx < cnt) ? st[idx] : -1;
    }
#pragma unroll
    for (int k = 0; k < K2; ++k) {
        myrank[k] = (myrec[k] >= 0) ? atomicAdd(&hist[myrec[k] & 127], 1) : 0;
    }
    __syncthreads();
    if (tid < 128) ssc[tid] = hist[tid];
    __syncthreads();
    for (int off = 1; off < 128; off <<= 1) {
        int t = (tid < 128 && tid >= off) ? ssc[tid - off] : 0;
        __syncthreads();
        if (tid < 128) ssc[tid] += t;
        __syncthreads();
    }
    // ssc inclusive; exclusive base = ssc[r] - hist[r]
    if (tid < 128) {
        int row = row0 + tid;
        if (row < N_NODES) {
            int deg = hist[tid];
            rowptr[row] = fb + ssc[tid] - deg;
            dinv[row] = (deg > 0) ? rsqrtf((float)deg) : 0.0f;
        }
    }
    if (bin == 0 && tid == 0) rowptr[N_NODES] = N_EDGES;
    __syncthreads();
#pragma unroll
    for (int k = 0; k < K2; ++k) {
        if (myrec[k] >= 0) {
            int r = myrec[k] & 127;
            int c = ((unsigned)myrec[k]) >> 7;
            edgesF[fb + ssc[r] - hist[r] + myrank[k]] = c;
        }
    }
}

// ---------------- xls = bf16(dinv[row] * (x @ W.T + b)), MFMA 16x16x32 ----------------
__global__ __launch_bounds__(256) void gemm_mfma(const float* __restrict__ x,
                                                 const __hip_bfloat16* __restrict__ Wb,
                                                 const float* __restrict__ b,
                                                 const float* __restrict__ dinv,
                                                 __hip_bfloat16* __restrict__ xl) {
    __shared__ __hip_bfloat16 lds[4][16][136];   // per-wave transpose buffer
    int tid = threadIdx.x;
    int w = tid >> 6;
    int l = tid & 63;
    int lm = l & 15;
    int kb = l >> 4;
    int bm = blockIdx.x * 64 + w * 16;

    int row = bm + lm;
    if (row >= N_NODES) row = N_NODES - 1;       // dup compute; stores guarded
    const float* xr = x + (size_t)row * D;

    short8v a[4];
#pragma unroll
    for (int ks = 0; ks < 4; ++ks) {
        const float* p = xr + ks * 32 + kb * 8;
        float4 u = *(const float4*)p;
        float4 v = *(const float4*)(p + 4);
        short8v t;
        t[0] = f2bf(u.x); t[1] = f2bf(u.y); t[2] = f2bf(u.z); t[3] = f2bf(u.w);
        t[4] = f2bf(v.x); t[5] = f2bf(v.y); t[6] = f2bf(v.z); t[7] = f2bf(v.w);
        a[ks] = t;
    }

    f32x4 acc[8];
#pragma unroll
    for (int nf = 0; nf < 8; ++nf) {
        acc[nf][0] = 0.f; acc[nf][1] = 0.f; acc[nf][2] = 0.f; acc[nf][3] = 0.f;
    }

    const short8v* Wv = reinterpret_cast<const short8v*>(Wb);
#pragma unroll
    for (int ks = 0; ks < 4; ++ks) {
#pragma unroll
        for (int nf = 0; nf < 8; ++nf) {
            short8v bf = Wv[(nf * 16 + lm) * 16 + ks * 4 + kb];
            acc[nf] = __builtin_amdgcn_mfma_f32_16x16x32_bf16(a[ks], bf, acc[nf], 0, 0, 0);
        }
    }

    // per-output-row dinv scale (D row = kb*4 + j)
    float drj[4];
#pragma unroll
    for (int j = 0; j < 4; ++j) {
        int rr = bm + kb * 4 + j;
        if (rr >= N_NODES) rr = N_NODES - 1;
        drj[j] = dinv[rr];
    }

#pragma unroll
    for (int nf = 0; nf < 8; ++nf) {
        float bias = b[nf * 16 + lm];
#pragma unroll
        for (int j = 0; j < 4; ++j) {
            lds[w][kb * 4 + j][nf * 16 + lm] =
                __float2bfloat16((acc[nf][j] + bias) * drj[j]);
        }
    }
    __syncthreads();
#pragma unroll
    for (int it = 0; it < 4; ++it) {
        int idx = it * 64 + l;
        int r = idx >> 4;
        int ch = (idx & 15) * 8;
        int grow = bm + r;
        if (grow < N_NODES)
            *(short8v*)&xl[(size_t)grow * D + ch] = *(const short8v*)&lds[w][r][ch];
    }
}

// ---------------- aggregation: wave per node, 16 edges in flight ----------------
// out[r] = dinv[r] * sum_e xls[c_e]   (dinv[c] pre-folded into xls)
static __device__ __forceinline__ void acc8(float* acc, uint4 v) {
    acc[0] += __uint_as_float(v.x << 16);
    acc[1] += __uint_as_float(v.x & 0xffff0000u);
    acc[2] += __uint_as_float(v.y << 16);
    acc[3] += __uint_as_float(v.y & 0xffff0000u);
    acc[4] += __uint_as_float(v.z << 16);
    acc[5] += __uint_as_float(v.z & 0xffff0000u);
    acc[6] += __uint_as_float(v.w << 16);
    acc[7] += __uint_as_float(v.w & 0xffff0000u);
}

__global__ __launch_bounds__(256) void aggregate(const int* __restrict__ edges,
                                                 const int* __restrict__ rowptr,
                                                 const float* __restrict__ dinv,
                                                 const __hip_bfloat16* __restrict__ xl,
                                                 float* __restrict__ out) {
    int gw = (blockIdx.x * 256 + threadIdx.x) >> 6;
    int lane = threadIdx.x & 63;
    if (gw >= N_NODES) return;
    int g = lane >> 4;          // edge-slot group 0..3
    int q = lane & 15;          // 16B chunk within row (8 channels)
    int s = rowptr[gw];
    int e = rowptr[gw + 1];

    float acc[8];
#pragma unroll
    for (int k = 0; k < 8; ++k) acc[k] = 0.0f;

    int i = s;
    // 16 edges per step: 4 independent index loads + 4 independent gathers
    for (; i + 16 <= e; i += 16) {
        int c0 = edges[i + g];
        int c1 = edges[i + 4 + g];
        int c2 = edges[i + 8 + g];
        int c3 = edges[i + 12 + g];
        uint4 v0 = *(const uint4*)&xl[(size_t)c0 * D + q * 8];
        uint4 v1 = *(const uint4*)&xl[(size_t)c1 * D + q * 8];
        uint4 v2 = *(const uint4*)&xl[(size_t)c2 * D + q * 8];
        uint4 v3 = *(const uint4*)&xl[(size_t)c3 * D + q * 8];
        acc8(acc, v0); acc8(acc, v1); acc8(acc, v2); acc8(acc, v3);
    }
    for (; i + 4 <= e; i += 4) {
        int c = edges[i + g];
        uint4 v = *(const uint4*)&xl[(size_t)c * D + q * 8];
        acc8(acc, v);
    }
    int rem = e - i;
    if (g < rem) {
        int c = edges[i + g];
        uint4 v = *(const uint4*)&xl[(size_t)c * D + q * 8];
        acc8(acc, v);
    }
    // reduce across the 4 groups (lanes l, l^16, l^32, l^48)
#pragma unroll
    for (int k = 0; k < 8; ++k) {
        acc[k] += __shfl_xor(acc[k], 16, 64);
        acc[k] += __shfl_xor(acc[k], 32, 64);
    }
    if (lane < 16) {
        float dr = dinv[gw];
        float4 o0 = make_float4(dr * acc[0], dr * acc[1], dr * acc[2], dr * acc[3]);
        float4 o1 = make_float4(dr * acc[4], dr * acc[5], dr * acc[6], dr * acc[7]);
        float* op = &out[(size_t)gw * D + q * 8];
        *(float4*)op = o0;
        *(float4*)(op + 4) = o1;
    }
}

extern "C" void kernel_launch(void* const* d_in, const int* in_sizes, int n_in,
                              void* d_out, int out_size, void* d_ws, size_t ws_size,
                              hipStream_t stream) {
    const float* x  = (const float*)d_in[0];
    const int*   ei = (const int*)d_in[1];
    const float* W  = (const float*)d_in[2];
    const float* b  = (const float*)d_in[3];
    float* out = (float*)d_out;

    // workspace layout (4-byte units)
    unsigned int* ws = (unsigned int*)d_ws;
    __hip_bfloat16* xl = (__hip_bfloat16*)ws;                 // 12.8M bf16 = 6.4M u32
    __hip_bfloat16* Wb = (__hip_bfloat16*)(ws + 6400000);     // 16384 bf16 = 8192 u32
    float* dinv    = (float*)(ws + 6408192);                  // 100,096
    int*   rowptr  = (int*)(ws + 6508288);                    // 100,160 (needs 100,001)
    int*   cursor  = (int*)(ws + 6608448);                    // 800 (NB=782)
    int*   edgesF  = (int*)(ws + 6610048);                    // 3.2M ints
    int*   staging = (int*)(ws + 9810048);                    // NB*CAP = 4,003,840 ints
    // total ≈ 13.8M u32 ≈ 55.3 MB

    convW_init<<<(D * D + 255) / 256, 256, 0, stream>>>(W, Wb, cursor);

    const int pblocks = (N_EDGES + 256 * EPB - 1) / (256 * EPB);   // 391
    partition_k<<<pblocks, 256, 0, stream>>>(ei, cursor, staging);

    pass2_k<<<NB, 256, 0, stream>>>(staging, cursor, rowptr, dinv, edgesF);

    gemm_mfma<<<(N_NODES + 63) / 64, 256, 0, stream>>>(x, Wb, b, dinv, xl);

    aggregate<<<(N_NODES * 64 + 255) / 256, 256, 0, stream>>>(
        edgesF, rowptr, dinv, xl, out);
}